// Round 1
// baseline (533.662 us; speedup 1.0000x reference)
//
#include <hip/hip_runtime.h>

// REConv forward: out = (indeg^-1/2) * scatter_sum_dst( (outdeg^-1/2 * wtype[type]) * (feat @ W) [src] ) + bias
// F_IN = F_OUT = 64 hardcoded.

#define THREADS 256

__global__ void deg_kernel(const int* __restrict__ src, const int* __restrict__ dst,
                           unsigned int* __restrict__ outdeg, unsigned int* __restrict__ indeg,
                           int E) {
    int e = blockIdx.x * blockDim.x + threadIdx.x;
    if (e < E) {
        atomicAdd(&outdeg[src[e]], 1u);
        atomicAdd(&indeg[dst[e]], 1u);
    }
}

// One thread per node-row: h[row][:] = (feat[row] @ W) * (rsqrt(max(outdeg,1)) * wtype[type[row]])
__global__ void transform_kernel(const float* __restrict__ feat, const float* __restrict__ weight,
                                 const float* __restrict__ wtype, const int* __restrict__ tinfo,
                                 const unsigned int* __restrict__ outdeg,
                                 float* __restrict__ h, int N) {
    __shared__ float W[64 * 64];
    int t = threadIdx.x;
    // Stage W (16 KB) into LDS, coalesced float4 loads.
    const float4* w4 = (const float4*)weight;
    float4* W4 = (float4*)W;
#pragma unroll
    for (int i = 0; i < 4; ++i) W4[t + i * 256] = w4[t + i * 256];
    __syncthreads();

    int row = blockIdx.x * blockDim.x + t;
    if (row >= N) return;

    float s = rsqrtf(fmaxf((float)outdeg[row], 1.0f)) * wtype[tinfo[row]];

    float acc[64];
#pragma unroll
    for (int j = 0; j < 64; ++j) acc[j] = 0.0f;

    const float4* frow = (const float4*)(feat + (size_t)row * 64);
    float fr[64];
#pragma unroll
    for (int k4 = 0; k4 < 16; ++k4) {
        float4 v = frow[k4];
        fr[k4 * 4 + 0] = v.x; fr[k4 * 4 + 1] = v.y;
        fr[k4 * 4 + 2] = v.z; fr[k4 * 4 + 3] = v.w;
    }

    for (int k = 0; k < 64; ++k) {
        float a = fr[k];
        const float4* wr = (const float4*)&W[k * 64];
#pragma unroll
        for (int j4 = 0; j4 < 16; ++j4) {
            float4 w = wr[j4];  // wave-uniform LDS address -> broadcast, no conflicts
            acc[j4 * 4 + 0] += a * w.x;
            acc[j4 * 4 + 1] += a * w.y;
            acc[j4 * 4 + 2] += a * w.z;
            acc[j4 * 4 + 3] += a * w.w;
        }
    }

    float4* hrow = (float4*)(h + (size_t)row * 64);
#pragma unroll
    for (int j4 = 0; j4 < 16; ++j4) {
        float4 v;
        v.x = acc[j4 * 4 + 0] * s;
        v.y = acc[j4 * 4 + 1] * s;
        v.z = acc[j4 * 4 + 2] * s;
        v.w = acc[j4 * 4 + 3] * s;
        hrow[j4] = v;
    }
}

// One wave (64 lanes) per edge; lane = feature index. Coalesced 256B gather + 256B atomic scatter.
__global__ void scatter_kernel(const int* __restrict__ src, const int* __restrict__ dst,
                               const float* __restrict__ h, float* __restrict__ out, int E) {
    long long idx = (long long)blockIdx.x * blockDim.x + threadIdx.x;
    int e = (int)(idx >> 6);
    int f = (int)(idx & 63);
    if (e < E) {
        int s = src[e];
        int d = dst[e];
        float v = h[(size_t)s * 64 + f];
        atomicAdd(&out[(size_t)d * 64 + f], v);
    }
}

// out[n][f] = out[n][f] * rsqrt(max(indeg,1)) + bias[f]; one thread per float4.
__global__ void finalize_kernel(float* __restrict__ out, const unsigned int* __restrict__ indeg,
                                const float* __restrict__ bias, int N) {
    int idx = blockIdx.x * blockDim.x + threadIdx.x;
    if (idx >= N * 16) return;
    int n = idx >> 4;
    int f4 = idx & 15;
    float s = rsqrtf(fmaxf((float)indeg[n], 1.0f));
    float4 v = ((float4*)out)[idx];
    float4 b = ((const float4*)bias)[f4];
    v.x = v.x * s + b.x;
    v.y = v.y * s + b.y;
    v.z = v.z * s + b.z;
    v.w = v.w * s + b.w;
    ((float4*)out)[idx] = v;
}

extern "C" void kernel_launch(void* const* d_in, const int* in_sizes, int n_in,
                              void* d_out, int out_size, void* d_ws, size_t ws_size,
                              hipStream_t stream) {
    const float* feat   = (const float*)d_in[0];
    const float* weight = (const float*)d_in[1];
    const float* wtype  = (const float*)d_in[2];
    const float* bias   = (const float*)d_in[3];
    const int*   src    = (const int*)d_in[4];
    const int*   dst    = (const int*)d_in[5];
    const int*   tinfo  = (const int*)d_in[6];

    int E = in_sizes[4];
    int N = in_sizes[6];
    float* out = (float*)d_out;

    // Workspace layout: h [N*64 f32] | outdeg [N u32] | indeg [N u32]
    char* ws = (char*)d_ws;
    float* h = (float*)ws;
    unsigned int* outdeg = (unsigned int*)(ws + (size_t)N * 64 * sizeof(float));
    unsigned int* indeg  = outdeg + N;

    hipMemsetAsync(out, 0, (size_t)out_size * sizeof(float), stream);
    hipMemsetAsync(outdeg, 0, (size_t)N * 2 * sizeof(unsigned int), stream);

    deg_kernel<<<(E + THREADS - 1) / THREADS, THREADS, 0, stream>>>(src, dst, outdeg, indeg, E);
    transform_kernel<<<(N + THREADS - 1) / THREADS, THREADS, 0, stream>>>(
        feat, weight, wtype, tinfo, outdeg, h, N);

    long long scatter_threads = (long long)E * 64;
    int scatter_blocks = (int)((scatter_threads + THREADS - 1) / THREADS);
    scatter_kernel<<<scatter_blocks, THREADS, 0, stream>>>(src, dst, h, out, E);

    finalize_kernel<<<(N * 16 + THREADS - 1) / THREADS, THREADS, 0, stream>>>(out, indeg, bias, N);
}

// Round 2
// 369.385 us; speedup vs baseline: 1.4447x; 1.4447x over previous
//
#include <hip/hip_runtime.h>

// REConv forward via dst-CSR gather (no f32 atomics):
//   1. deg_kernel: indeg/outdeg histograms (u32 atomics)
//   2. transform:  h = (feat * outdeg^-1/2 * wtype[type]) @ W
//   3. scan1/2/3:  exclusive prefix sum of indeg -> offsets, cursor=offsets
//   4. bucket:     sorted_src[atomicAdd(cursor[dst])] = src   (CSR build)
//   5. gather:     one wave per dst node, register accumulate, fused indeg^-1/2 + bias
// F_IN = F_OUT = 64 hardcoded.

#define THREADS 256
#define SCAN_CHUNK 1024  // 256 threads x 4 elements

__global__ void deg_kernel(const int* __restrict__ src, const int* __restrict__ dst,
                           unsigned int* __restrict__ outdeg, unsigned int* __restrict__ indeg,
                           int E) {
    int e = blockIdx.x * blockDim.x + threadIdx.x;
    if (e < E) {
        atomicAdd(&outdeg[src[e]], 1u);
        atomicAdd(&indeg[dst[e]], 1u);
    }
}

__global__ void transform_kernel(const float* __restrict__ feat, const float* __restrict__ weight,
                                 const float* __restrict__ wtype, const int* __restrict__ tinfo,
                                 const unsigned int* __restrict__ outdeg,
                                 float* __restrict__ h, int N) {
    __shared__ float W[64 * 64];
    int t = threadIdx.x;
    const float4* w4 = (const float4*)weight;
    float4* W4 = (float4*)W;
#pragma unroll
    for (int i = 0; i < 4; ++i) W4[t + i * 256] = w4[t + i * 256];
    __syncthreads();

    int row = blockIdx.x * blockDim.x + t;
    if (row >= N) return;

    float s = rsqrtf(fmaxf((float)outdeg[row], 1.0f)) * wtype[tinfo[row]];

    float acc[64];
#pragma unroll
    for (int j = 0; j < 64; ++j) acc[j] = 0.0f;

    const float4* frow = (const float4*)(feat + (size_t)row * 64);
    for (int k4 = 0; k4 < 16; ++k4) {
        float4 a4 = frow[k4];
#pragma unroll
        for (int kk = 0; kk < 4; ++kk) {
            float a = (kk == 0) ? a4.x : (kk == 1) ? a4.y : (kk == 2) ? a4.z : a4.w;
            const float4* wr = (const float4*)&W[(k4 * 4 + kk) * 64];
#pragma unroll
            for (int j4 = 0; j4 < 16; ++j4) {
                float4 w = wr[j4];  // wave-uniform LDS address -> broadcast
                acc[j4 * 4 + 0] += a * w.x;
                acc[j4 * 4 + 1] += a * w.y;
                acc[j4 * 4 + 2] += a * w.z;
                acc[j4 * 4 + 3] += a * w.w;
            }
        }
    }

    float4* hrow = (float4*)(h + (size_t)row * 64);
#pragma unroll
    for (int j4 = 0; j4 < 16; ++j4) {
        float4 v;
        v.x = acc[j4 * 4 + 0] * s;
        v.y = acc[j4 * 4 + 1] * s;
        v.z = acc[j4 * 4 + 2] * s;
        v.w = acc[j4 * 4 + 3] * s;
        hrow[j4] = v;
    }
}

// Per-chunk exclusive scan of indeg -> offsets; chunk totals -> blockSums.
__global__ void scan1_kernel(const unsigned int* __restrict__ indeg,
                             unsigned int* __restrict__ offsets,
                             unsigned int* __restrict__ blockSums, int N) {
    __shared__ unsigned int sdata[256];
    int t = threadIdx.x;
    int base = blockIdx.x * SCAN_CHUNK;
    unsigned int v[4];
    unsigned int s = 0;
#pragma unroll
    for (int i = 0; i < 4; ++i) {
        int idx = base + t * 4 + i;
        v[i] = (idx < N) ? indeg[idx] : 0u;
        s += v[i];
    }
    sdata[t] = s;
    __syncthreads();
    for (int off = 1; off < 256; off <<= 1) {
        unsigned int x = (t >= off) ? sdata[t - off] : 0u;
        __syncthreads();
        sdata[t] += x;
        __syncthreads();
    }
    if (t == 255) blockSums[blockIdx.x] = sdata[255];
    unsigned int run = sdata[t] - s;  // exclusive prefix of this thread's 4-group
#pragma unroll
    for (int i = 0; i < 4; ++i) {
        int idx = base + t * 4 + i;
        if (idx < N) offsets[idx] = run;
        run += v[i];
    }
}

// Single-block exclusive scan of blockSums (nb <= 1024).
__global__ void scan2_kernel(unsigned int* __restrict__ blockSums, int nb) {
    __shared__ unsigned int sdata[1024];
    int t = threadIdx.x;
    unsigned int v = (t < nb) ? blockSums[t] : 0u;
    sdata[t] = v;
    __syncthreads();
    for (int off = 1; off < 1024; off <<= 1) {
        unsigned int x = (t >= off) ? sdata[t - off] : 0u;
        __syncthreads();
        sdata[t] += x;
        __syncthreads();
    }
    if (t < nb) blockSums[t] = sdata[t] - v;
}

// offsets += chunk base; cursor = offsets.
__global__ void scan3_kernel(unsigned int* __restrict__ offsets,
                             const unsigned int* __restrict__ blockSums,
                             unsigned int* __restrict__ cursor, int N) {
    int i = blockIdx.x * blockDim.x + threadIdx.x;
    if (i < N) {
        unsigned int o = offsets[i] + blockSums[i / SCAN_CHUNK];
        offsets[i] = o;
        cursor[i] = o;
    }
}

__global__ void bucket_kernel(const int* __restrict__ src, const int* __restrict__ dst,
                              unsigned int* __restrict__ cursor,
                              int* __restrict__ sorted_src, int E) {
    int e = blockIdx.x * blockDim.x + threadIdx.x;
    if (e < E) {
        int d = dst[e];
        unsigned int pos = atomicAdd(&cursor[d], 1u);
        sorted_src[pos] = src[e];
    }
}

// One wave per dst node; lane = feature. Register accumulate over in-edges,
// fused right-norm + bias, single coalesced row write.
__global__ void gather_kernel(const int* __restrict__ sorted_src,
                              const unsigned int* __restrict__ offsets,
                              const unsigned int* __restrict__ indeg,
                              const float* __restrict__ h, const float* __restrict__ bias,
                              float* __restrict__ out, int N) {
    int lane = threadIdx.x & 63;
    int node = blockIdx.x * (blockDim.x >> 6) + (threadIdx.x >> 6);
    if (node >= N) return;
    unsigned int beg = offsets[node];
    unsigned int cnt = indeg[node];
    unsigned int i = beg, end = beg + cnt;
    float acc = 0.0f;
    for (; i + 4 <= end; i += 4) {
        int s0 = sorted_src[i + 0];
        int s1 = sorted_src[i + 1];
        int s2 = sorted_src[i + 2];
        int s3 = sorted_src[i + 3];
        float v0 = h[(size_t)s0 * 64 + lane];
        float v1 = h[(size_t)s1 * 64 + lane];
        float v2 = h[(size_t)s2 * 64 + lane];
        float v3 = h[(size_t)s3 * 64 + lane];
        acc += (v0 + v1) + (v2 + v3);
    }
    for (; i < end; ++i) acc += h[(size_t)sorted_src[i] * 64 + lane];
    float sc = rsqrtf(fmaxf((float)cnt, 1.0f));
    out[(size_t)node * 64 + lane] = acc * sc + bias[lane];
}

extern "C" void kernel_launch(void* const* d_in, const int* in_sizes, int n_in,
                              void* d_out, int out_size, void* d_ws, size_t ws_size,
                              hipStream_t stream) {
    const float* feat   = (const float*)d_in[0];
    const float* weight = (const float*)d_in[1];
    const float* wtype  = (const float*)d_in[2];
    const float* bias   = (const float*)d_in[3];
    const int*   src    = (const int*)d_in[4];
    const int*   dst    = (const int*)d_in[5];
    const int*   tinfo  = (const int*)d_in[6];

    int E = in_sizes[4];
    int N = in_sizes[6];
    float* out = (float*)d_out;

    // Workspace: h [N*64 f32] | outdeg | indeg | offsets | cursor [N u32 each] | blockSums [1024 u32] | sorted_src [E i32]
    char* ws = (char*)d_ws;
    float* h = (float*)ws;                              ws += (size_t)N * 64 * sizeof(float);
    unsigned int* outdeg    = (unsigned int*)ws;        ws += (size_t)N * sizeof(unsigned int);
    unsigned int* indeg     = (unsigned int*)ws;        ws += (size_t)N * sizeof(unsigned int);
    unsigned int* offsets   = (unsigned int*)ws;        ws += (size_t)N * sizeof(unsigned int);
    unsigned int* cursor    = (unsigned int*)ws;        ws += (size_t)N * sizeof(unsigned int);
    unsigned int* blockSums = (unsigned int*)ws;        ws += 1024 * sizeof(unsigned int);
    int* sorted_src = (int*)ws;

    hipMemsetAsync(outdeg, 0, (size_t)N * 2 * sizeof(unsigned int), stream);  // outdeg+indeg contiguous

    deg_kernel<<<(E + THREADS - 1) / THREADS, THREADS, 0, stream>>>(src, dst, outdeg, indeg, E);
    transform_kernel<<<(N + THREADS - 1) / THREADS, THREADS, 0, stream>>>(
        feat, weight, wtype, tinfo, outdeg, h, N);

    int nb = (N + SCAN_CHUNK - 1) / SCAN_CHUNK;
    scan1_kernel<<<nb, 256, 0, stream>>>(indeg, offsets, blockSums, N);
    scan2_kernel<<<1, 1024, 0, stream>>>(blockSums, nb);
    scan3_kernel<<<(N + THREADS - 1) / THREADS, THREADS, 0, stream>>>(offsets, blockSums, cursor, N);

    bucket_kernel<<<(E + THREADS - 1) / THREADS, THREADS, 0, stream>>>(src, dst, cursor, sorted_src, E);

    int waves_per_block = THREADS / 64;
    int gather_blocks = (N + waves_per_block - 1) / waves_per_block;
    gather_kernel<<<gather_blocks, THREADS, 0, stream>>>(sorted_src, offsets, indeg, h, bias, out, N);
}

// Round 3
// 311.372 us; speedup vs baseline: 1.7139x; 1.1863x over previous
//
#include <hip/hip_runtime.h>

// REConv forward via dst-CSR gather, XCD-teamed histogram/bucket scatter.
//   1. deg_team:   8 node-regions; team blockIdx%8 (maps to XCD) handles only its region's
//                  atomics -> counter lines stay XCD-L2-local (no cross-XCD ping-pong).
//   2. transform:  h = (feat * outdeg^-1/2 * wtype[type]) @ W
//   3. scan1/2/3:  exclusive prefix sum of indeg -> offsets, cursor=offsets
//   4. bucket_team: same teaming; each region's sorted_src slice written by one XCD only,
//                  so scattered 4B stores combine in that XCD's L2 (was 106MB HBM writes).
//   5. gather:     one wave per dst node, register accumulate, fused indeg^-1/2 + bias
// F_IN = F_OUT = 64 hardcoded.

#define THREADS 256
#define SCAN_CHUNK 1024
#define NTEAM 8
#define BLOCKS_PER_TEAM 128

__global__ void deg_team_kernel(const int* __restrict__ src, const int* __restrict__ dst,
                                unsigned int* __restrict__ outdeg, unsigned int* __restrict__ indeg,
                                int E, int regsz) {
    int team = blockIdx.x & (NTEAM - 1);
    int blk  = blockIdx.x >> 3;
    int lo = team * regsz, hi = lo + regsz;
    int tid = blk * blockDim.x + threadIdx.x;
    int stride = (gridDim.x >> 3) * blockDim.x;
    for (int e = tid; e < E; e += stride) {
        int s = src[e];
        int d = dst[e];
        if (s >= lo && s < hi) atomicAdd(&outdeg[s], 1u);
        if (d >= lo && d < hi) atomicAdd(&indeg[d], 1u);
    }
}

__global__ void transform_kernel(const float* __restrict__ feat, const float* __restrict__ weight,
                                 const float* __restrict__ wtype, const int* __restrict__ tinfo,
                                 const unsigned int* __restrict__ outdeg,
                                 float* __restrict__ h, int N) {
    __shared__ float W[64 * 64];
    int t = threadIdx.x;
    const float4* w4 = (const float4*)weight;
    float4* W4 = (float4*)W;
#pragma unroll
    for (int i = 0; i < 4; ++i) W4[t + i * 256] = w4[t + i * 256];
    __syncthreads();

    int row = blockIdx.x * blockDim.x + t;
    if (row >= N) return;

    float s = rsqrtf(fmaxf((float)outdeg[row], 1.0f)) * wtype[tinfo[row]];

    float acc[64];
#pragma unroll
    for (int j = 0; j < 64; ++j) acc[j] = 0.0f;

    const float4* frow = (const float4*)(feat + (size_t)row * 64);
    for (int k4 = 0; k4 < 16; ++k4) {
        float4 a4 = frow[k4];
#pragma unroll
        for (int kk = 0; kk < 4; ++kk) {
            float a = (kk == 0) ? a4.x : (kk == 1) ? a4.y : (kk == 2) ? a4.z : a4.w;
            const float4* wr = (const float4*)&W[(k4 * 4 + kk) * 64];
#pragma unroll
            for (int j4 = 0; j4 < 16; ++j4) {
                float4 w = wr[j4];  // wave-uniform LDS address -> broadcast
                acc[j4 * 4 + 0] += a * w.x;
                acc[j4 * 4 + 1] += a * w.y;
                acc[j4 * 4 + 2] += a * w.z;
                acc[j4 * 4 + 3] += a * w.w;
            }
        }
    }

    float4* hrow = (float4*)(h + (size_t)row * 64);
#pragma unroll
    for (int j4 = 0; j4 < 16; ++j4) {
        float4 v;
        v.x = acc[j4 * 4 + 0] * s;
        v.y = acc[j4 * 4 + 1] * s;
        v.z = acc[j4 * 4 + 2] * s;
        v.w = acc[j4 * 4 + 3] * s;
        hrow[j4] = v;
    }
}

__global__ void scan1_kernel(const unsigned int* __restrict__ indeg,
                             unsigned int* __restrict__ offsets,
                             unsigned int* __restrict__ blockSums, int N) {
    __shared__ unsigned int sdata[256];
    int t = threadIdx.x;
    int base = blockIdx.x * SCAN_CHUNK;
    unsigned int v[4];
    unsigned int s = 0;
#pragma unroll
    for (int i = 0; i < 4; ++i) {
        int idx = base + t * 4 + i;
        v[i] = (idx < N) ? indeg[idx] : 0u;
        s += v[i];
    }
    sdata[t] = s;
    __syncthreads();
    for (int off = 1; off < 256; off <<= 1) {
        unsigned int x = (t >= off) ? sdata[t - off] : 0u;
        __syncthreads();
        sdata[t] += x;
        __syncthreads();
    }
    if (t == 255) blockSums[blockIdx.x] = sdata[255];
    unsigned int run = sdata[t] - s;
#pragma unroll
    for (int i = 0; i < 4; ++i) {
        int idx = base + t * 4 + i;
        if (idx < N) offsets[idx] = run;
        run += v[i];
    }
}

__global__ void scan2_kernel(unsigned int* __restrict__ blockSums, int nb) {
    __shared__ unsigned int sdata[1024];
    int t = threadIdx.x;
    unsigned int v = (t < nb) ? blockSums[t] : 0u;
    sdata[t] = v;
    __syncthreads();
    for (int off = 1; off < 1024; off <<= 1) {
        unsigned int x = (t >= off) ? sdata[t - off] : 0u;
        __syncthreads();
        sdata[t] += x;
        __syncthreads();
    }
    if (t < nb) blockSums[t] = sdata[t] - v;
}

__global__ void scan3_kernel(unsigned int* __restrict__ offsets,
                             const unsigned int* __restrict__ blockSums,
                             unsigned int* __restrict__ cursor, int N) {
    int i = blockIdx.x * blockDim.x + threadIdx.x;
    if (i < N) {
        unsigned int o = offsets[i] + blockSums[i / SCAN_CHUNK];
        offsets[i] = o;
        cursor[i] = o;
    }
}

__global__ void bucket_team_kernel(const int* __restrict__ src, const int* __restrict__ dst,
                                   unsigned int* __restrict__ cursor,
                                   int* __restrict__ sorted_src, int E, int regsz) {
    int team = blockIdx.x & (NTEAM - 1);
    int blk  = blockIdx.x >> 3;
    int lo = team * regsz, hi = lo + regsz;
    int tid = blk * blockDim.x + threadIdx.x;
    int stride = (gridDim.x >> 3) * blockDim.x;
    for (int e = tid; e < E; e += stride) {
        int d = dst[e];
        if (d >= lo && d < hi) {
            unsigned int pos = atomicAdd(&cursor[d], 1u);
            sorted_src[pos] = src[e];   // pos lies in this team's contiguous slice -> XCD-local line
        }
    }
}

__global__ void gather_kernel(const int* __restrict__ sorted_src,
                              const unsigned int* __restrict__ offsets,
                              const unsigned int* __restrict__ indeg,
                              const float* __restrict__ h, const float* __restrict__ bias,
                              float* __restrict__ out, int N) {
    int lane = threadIdx.x & 63;
    int node = blockIdx.x * (blockDim.x >> 6) + (threadIdx.x >> 6);
    if (node >= N) return;
    unsigned int beg = offsets[node];
    unsigned int cnt = indeg[node];
    unsigned int i = beg, end = beg + cnt;
    float acc = 0.0f;
    for (; i + 4 <= end; i += 4) {
        int s0 = sorted_src[i + 0];
        int s1 = sorted_src[i + 1];
        int s2 = sorted_src[i + 2];
        int s3 = sorted_src[i + 3];
        float v0 = h[(size_t)s0 * 64 + lane];
        float v1 = h[(size_t)s1 * 64 + lane];
        float v2 = h[(size_t)s2 * 64 + lane];
        float v3 = h[(size_t)s3 * 64 + lane];
        acc += (v0 + v1) + (v2 + v3);
    }
    for (; i < end; ++i) acc += h[(size_t)sorted_src[i] * 64 + lane];
    float sc = rsqrtf(fmaxf((float)cnt, 1.0f));
    out[(size_t)node * 64 + lane] = acc * sc + bias[lane];
}

extern "C" void kernel_launch(void* const* d_in, const int* in_sizes, int n_in,
                              void* d_out, int out_size, void* d_ws, size_t ws_size,
                              hipStream_t stream) {
    const float* feat   = (const float*)d_in[0];
    const float* weight = (const float*)d_in[1];
    const float* wtype  = (const float*)d_in[2];
    const float* bias   = (const float*)d_in[3];
    const int*   src    = (const int*)d_in[4];
    const int*   dst    = (const int*)d_in[5];
    const int*   tinfo  = (const int*)d_in[6];

    int E = in_sizes[4];
    int N = in_sizes[6];
    float* out = (float*)d_out;
    int regsz = (N + NTEAM - 1) / NTEAM;

    // Workspace: h | outdeg | indeg | offsets | cursor | blockSums | sorted_src
    char* ws = (char*)d_ws;
    float* h = (float*)ws;                              ws += (size_t)N * 64 * sizeof(float);
    unsigned int* outdeg    = (unsigned int*)ws;        ws += (size_t)N * sizeof(unsigned int);
    unsigned int* indeg     = (unsigned int*)ws;        ws += (size_t)N * sizeof(unsigned int);
    unsigned int* offsets   = (unsigned int*)ws;        ws += (size_t)N * sizeof(unsigned int);
    unsigned int* cursor    = (unsigned int*)ws;        ws += (size_t)N * sizeof(unsigned int);
    unsigned int* blockSums = (unsigned int*)ws;        ws += 1024 * sizeof(unsigned int);
    int* sorted_src = (int*)ws;

    hipMemsetAsync(outdeg, 0, (size_t)N * 2 * sizeof(unsigned int), stream);

    int team_grid = NTEAM * BLOCKS_PER_TEAM;
    deg_team_kernel<<<team_grid, THREADS, 0, stream>>>(src, dst, outdeg, indeg, E, regsz);
    transform_kernel<<<(N + THREADS - 1) / THREADS, THREADS, 0, stream>>>(
        feat, weight, wtype, tinfo, outdeg, h, N);

    int nb = (N + SCAN_CHUNK - 1) / SCAN_CHUNK;
    scan1_kernel<<<nb, 256, 0, stream>>>(indeg, offsets, blockSums, N);
    scan2_kernel<<<1, 1024, 0, stream>>>(blockSums, nb);
    scan3_kernel<<<(N + THREADS - 1) / THREADS, THREADS, 0, stream>>>(offsets, blockSums, cursor, N);

    bucket_team_kernel<<<team_grid, THREADS, 0, stream>>>(src, dst, cursor, sorted_src, E, regsz);

    int waves_per_block = THREADS / 64;
    int gather_blocks = (N + waves_per_block - 1) / waves_per_block;
    gather_kernel<<<gather_blocks, THREADS, 0, stream>>>(sorted_src, offsets, indeg, h, bias, out, N);
}

// Round 4
// 307.407 us; speedup vs baseline: 1.7360x; 1.0129x over previous
//
#include <hip/hip_runtime.h>

// REConv forward via dst-CSR gather.
//   1. deg:        flat 1-edge/thread u32 histograms (atomics are memory-side RMWs;
//                  teaming doesn't help them and costs 8x reads + long loops -> reverted)
//   2. transform:  h = (feat * outdeg^-1/2 * wtype[type]) @ W
//   3. scan1/2/3:  exclusive prefix sum of indeg -> offsets, cursor=offsets
//   4. bucket_team: XCD-teamed so each region's sorted_src slice is written by one XCD
//                  (plain stores DO combine in the owning XCD's L2: 106MB -> ~13MB writes)
//   5. gather:     one wave per dst node, register accumulate, fused indeg^-1/2 + bias
// F_IN = F_OUT = 64 hardcoded.

#define THREADS 256
#define SCAN_CHUNK 1024
#define NTEAM 8
#define BLOCKS_PER_TEAM 256

__global__ void deg_kernel(const int* __restrict__ src, const int* __restrict__ dst,
                           unsigned int* __restrict__ outdeg, unsigned int* __restrict__ indeg,
                           int E) {
    int e = blockIdx.x * blockDim.x + threadIdx.x;
    if (e < E) {
        atomicAdd(&outdeg[src[e]], 1u);
        atomicAdd(&indeg[dst[e]], 1u);
    }
}

__global__ void transform_kernel(const float* __restrict__ feat, const float* __restrict__ weight,
                                 const float* __restrict__ wtype, const int* __restrict__ tinfo,
                                 const unsigned int* __restrict__ outdeg,
                                 float* __restrict__ h, int N) {
    __shared__ float W[64 * 64];
    int t = threadIdx.x;
    const float4* w4 = (const float4*)weight;
    float4* W4 = (float4*)W;
#pragma unroll
    for (int i = 0; i < 4; ++i) W4[t + i * 256] = w4[t + i * 256];
    __syncthreads();

    int row = blockIdx.x * blockDim.x + t;
    if (row >= N) return;

    float s = rsqrtf(fmaxf((float)outdeg[row], 1.0f)) * wtype[tinfo[row]];

    float acc[64];
#pragma unroll
    for (int j = 0; j < 64; ++j) acc[j] = 0.0f;

    const float4* frow = (const float4*)(feat + (size_t)row * 64);
    for (int k4 = 0; k4 < 16; ++k4) {
        float4 a4 = frow[k4];
#pragma unroll
        for (int kk = 0; kk < 4; ++kk) {
            float a = (kk == 0) ? a4.x : (kk == 1) ? a4.y : (kk == 2) ? a4.z : a4.w;
            const float4* wr = (const float4*)&W[(k4 * 4 + kk) * 64];
#pragma unroll
            for (int j4 = 0; j4 < 16; ++j4) {
                float4 w = wr[j4];  // wave-uniform LDS address -> broadcast
                acc[j4 * 4 + 0] += a * w.x;
                acc[j4 * 4 + 1] += a * w.y;
                acc[j4 * 4 + 2] += a * w.z;
                acc[j4 * 4 + 3] += a * w.w;
            }
        }
    }

    float4* hrow = (float4*)(h + (size_t)row * 64);
#pragma unroll
    for (int j4 = 0; j4 < 16; ++j4) {
        float4 v;
        v.x = acc[j4 * 4 + 0] * s;
        v.y = acc[j4 * 4 + 1] * s;
        v.z = acc[j4 * 4 + 2] * s;
        v.w = acc[j4 * 4 + 3] * s;
        hrow[j4] = v;
    }
}

__global__ void scan1_kernel(const unsigned int* __restrict__ indeg,
                             unsigned int* __restrict__ offsets,
                             unsigned int* __restrict__ blockSums, int N) {
    __shared__ unsigned int sdata[256];
    int t = threadIdx.x;
    int base = blockIdx.x * SCAN_CHUNK;
    unsigned int v[4];
    unsigned int s = 0;
#pragma unroll
    for (int i = 0; i < 4; ++i) {
        int idx = base + t * 4 + i;
        v[i] = (idx < N) ? indeg[idx] : 0u;
        s += v[i];
    }
    sdata[t] = s;
    __syncthreads();
    for (int off = 1; off < 256; off <<= 1) {
        unsigned int x = (t >= off) ? sdata[t - off] : 0u;
        __syncthreads();
        sdata[t] += x;
        __syncthreads();
    }
    if (t == 255) blockSums[blockIdx.x] = sdata[255];
    unsigned int run = sdata[t] - s;
#pragma unroll
    for (int i = 0; i < 4; ++i) {
        int idx = base + t * 4 + i;
        if (idx < N) offsets[idx] = run;
        run += v[i];
    }
}

__global__ void scan2_kernel(unsigned int* __restrict__ blockSums, int nb) {
    __shared__ unsigned int sdata[1024];
    int t = threadIdx.x;
    unsigned int v = (t < nb) ? blockSums[t] : 0u;
    sdata[t] = v;
    __syncthreads();
    for (int off = 1; off < 1024; off <<= 1) {
        unsigned int x = (t >= off) ? sdata[t - off] : 0u;
        __syncthreads();
        sdata[t] += x;
        __syncthreads();
    }
    if (t < nb) blockSums[t] = sdata[t] - v;
}

__global__ void scan3_kernel(unsigned int* __restrict__ offsets,
                             const unsigned int* __restrict__ blockSums,
                             unsigned int* __restrict__ cursor, int N) {
    int i = blockIdx.x * blockDim.x + threadIdx.x;
    if (i < N) {
        unsigned int o = offsets[i] + blockSums[i / SCAN_CHUNK];
        offsets[i] = o;
        cursor[i] = o;
    }
}

__global__ void bucket_team_kernel(const int* __restrict__ src, const int* __restrict__ dst,
                                   unsigned int* __restrict__ cursor,
                                   int* __restrict__ sorted_src, int E, int regsz) {
    int team = blockIdx.x & (NTEAM - 1);
    int blk  = blockIdx.x >> 3;
    int lo = team * regsz, hi = lo + regsz;
    int tid = blk * blockDim.x + threadIdx.x;
    int stride = (gridDim.x >> 3) * blockDim.x;
    for (int e = tid; e < E; e += stride) {
        int d = dst[e];
        if (d >= lo && d < hi) {
            unsigned int pos = atomicAdd(&cursor[d], 1u);
            sorted_src[pos] = src[e];   // team's contiguous slice -> XCD-local line, combines in L2
        }
    }
}

__global__ void gather_kernel(const int* __restrict__ sorted_src,
                              const unsigned int* __restrict__ offsets,
                              const unsigned int* __restrict__ indeg,
                              const float* __restrict__ h, const float* __restrict__ bias,
                              float* __restrict__ out, int N) {
    int lane = threadIdx.x & 63;
    int node = blockIdx.x * (blockDim.x >> 6) + (threadIdx.x >> 6);
    if (node >= N) return;
    unsigned int beg = offsets[node];
    unsigned int cnt = indeg[node];
    unsigned int i = beg, end = beg + cnt;
    float acc = 0.0f;
    for (; i + 4 <= end; i += 4) {
        int s0 = sorted_src[i + 0];
        int s1 = sorted_src[i + 1];
        int s2 = sorted_src[i + 2];
        int s3 = sorted_src[i + 3];
        float v0 = h[(size_t)s0 * 64 + lane];
        float v1 = h[(size_t)s1 * 64 + lane];
        float v2 = h[(size_t)s2 * 64 + lane];
        float v3 = h[(size_t)s3 * 64 + lane];
        acc += (v0 + v1) + (v2 + v3);
    }
    for (; i < end; ++i) acc += h[(size_t)sorted_src[i] * 64 + lane];
    float sc = rsqrtf(fmaxf((float)cnt, 1.0f));
    out[(size_t)node * 64 + lane] = acc * sc + bias[lane];
}

extern "C" void kernel_launch(void* const* d_in, const int* in_sizes, int n_in,
                              void* d_out, int out_size, void* d_ws, size_t ws_size,
                              hipStream_t stream) {
    const float* feat   = (const float*)d_in[0];
    const float* weight = (const float*)d_in[1];
    const float* wtype  = (const float*)d_in[2];
    const float* bias   = (const float*)d_in[3];
    const int*   src    = (const int*)d_in[4];
    const int*   dst    = (const int*)d_in[5];
    const int*   tinfo  = (const int*)d_in[6];

    int E = in_sizes[4];
    int N = in_sizes[6];
    float* out = (float*)d_out;
    int regsz = (N + NTEAM - 1) / NTEAM;

    // Workspace: h | outdeg | indeg | offsets | cursor | blockSums | sorted_src
    char* ws = (char*)d_ws;
    float* h = (float*)ws;                              ws += (size_t)N * 64 * sizeof(float);
    unsigned int* outdeg    = (unsigned int*)ws;        ws += (size_t)N * sizeof(unsigned int);
    unsigned int* indeg     = (unsigned int*)ws;        ws += (size_t)N * sizeof(unsigned int);
    unsigned int* offsets   = (unsigned int*)ws;        ws += (size_t)N * sizeof(unsigned int);
    unsigned int* cursor    = (unsigned int*)ws;        ws += (size_t)N * sizeof(unsigned int);
    unsigned int* blockSums = (unsigned int*)ws;        ws += 1024 * sizeof(unsigned int);
    int* sorted_src = (int*)ws;

    hipMemsetAsync(outdeg, 0, (size_t)N * 2 * sizeof(unsigned int), stream);

    deg_kernel<<<(E + THREADS - 1) / THREADS, THREADS, 0, stream>>>(src, dst, outdeg, indeg, E);
    transform_kernel<<<(N + THREADS - 1) / THREADS, THREADS, 0, stream>>>(
        feat, weight, wtype, tinfo, outdeg, h, N);

    int nb = (N + SCAN_CHUNK - 1) / SCAN_CHUNK;
    scan1_kernel<<<nb, 256, 0, stream>>>(indeg, offsets, blockSums, N);
    scan2_kernel<<<1, 1024, 0, stream>>>(blockSums, nb);
    scan3_kernel<<<(N + THREADS - 1) / THREADS, THREADS, 0, stream>>>(offsets, blockSums, cursor, N);

    int team_grid = NTEAM * BLOCKS_PER_TEAM;
    bucket_team_kernel<<<team_grid, THREADS, 0, stream>>>(src, dst, cursor, sorted_src, E, regsz);

    int waves_per_block = THREADS / 64;
    int gather_blocks = (N + waves_per_block - 1) / waves_per_block;
    gather_kernel<<<gather_blocks, THREADS, 0, stream>>>(sorted_src, offsets, indeg, h, bias, out, N);
}

// Round 5
// 209.313 us; speedup vs baseline: 2.5496x; 1.4686x over previous
//
#include <hip/hip_runtime.h>

// REConv forward via dst-CSR gather. Degree counting now via LDS histograms
// (ZERO global atomics — R4 measured scattered global atomics as memory-side
// RMWs at ~26G/s with full write-through; only reducing atomic COUNT helps).
//   1. hist:      block (slice s, region r) reads edge-slice s, LDS-histograms its
//                 region's src/dst hits packed in u32 (lo16=out, hi16=in; slice
//                 size 25k < 65536 -> overflow impossible); flush = plain stores.
//   2. reduce:    sum 64 slice-partials per bin -> outdeg, indeg.
//   3. transform: h = (feat * outdeg^-1/2 * wtype[type]) @ W  (h aliases partials)
//   4. scan1/2/3: exclusive prefix sum of indeg -> offsets, cursor=offsets
//   5. bucket_team: XCD-teamed scatter of src into dst-CSR (cursor atomics remain)
//   6. gather:    one wave per dst node, register accumulate, fused indeg^-1/2 + bias
// F_IN = F_OUT = 64 hardcoded.

#define THREADS 256
#define SCAN_CHUNK 1024
#define NSLICE 64
#define MAXREG 12800   // bins per region cap; LDS = 12800*4B = 51.2 KB
#define NTEAM 8
#define BLOCKS_PER_TEAM 256

// Packed per-slice histogram. Grid = NSLICE * nreg blocks; block = slice*nreg + region.
__global__ void hist_kernel(const int* __restrict__ src, const int* __restrict__ dst,
                            unsigned int* __restrict__ partial,
                            int E, int nreg, int regsz, int chunk, int N) {
    __shared__ unsigned int hist[MAXREG];
    int r = blockIdx.x % nreg;
    int s = blockIdx.x / nreg;
    int lo = r * regsz;
    int hi = min(lo + regsz, N);
    int nb = hi - lo;
    int t = threadIdx.x;
    for (int b = t; b < nb; b += THREADS) hist[b] = 0u;
    __syncthreads();

    int ebeg = s * chunk;
    int eend = min(E, ebeg + chunk);
    int main_end = ebeg + ((eend - ebeg) & ~3);
    for (int i = ebeg + t * 4; i + 3 < main_end + 4 && i + 3 < eend + 4 && i + 3 < main_end + 4; i += THREADS * 4) {
        if (i + 3 >= main_end) break;
        int4 s4 = *(const int4*)(src + i);
        int4 d4 = *(const int4*)(dst + i);
        if (s4.x >= lo && s4.x < hi) atomicAdd(&hist[s4.x - lo], 1u);
        if (s4.y >= lo && s4.y < hi) atomicAdd(&hist[s4.y - lo], 1u);
        if (s4.z >= lo && s4.z < hi) atomicAdd(&hist[s4.z - lo], 1u);
        if (s4.w >= lo && s4.w < hi) atomicAdd(&hist[s4.w - lo], 1u);
        if (d4.x >= lo && d4.x < hi) atomicAdd(&hist[d4.x - lo], 65536u);
        if (d4.y >= lo && d4.y < hi) atomicAdd(&hist[d4.y - lo], 65536u);
        if (d4.z >= lo && d4.z < hi) atomicAdd(&hist[d4.z - lo], 65536u);
        if (d4.w >= lo && d4.w < hi) atomicAdd(&hist[d4.w - lo], 65536u);
    }
    for (int i = main_end + t; i < eend; i += THREADS) {
        int sv = src[i], dv = dst[i];
        if (sv >= lo && sv < hi) atomicAdd(&hist[sv - lo], 1u);
        if (dv >= lo && dv < hi) atomicAdd(&hist[dv - lo], 65536u);
    }
    __syncthreads();
    unsigned int* pp = partial + (size_t)blockIdx.x * regsz;
    for (int b = t; b < nb; b += THREADS) pp[b] = hist[b];
}

__global__ void reduce_kernel(const unsigned int* __restrict__ partial,
                              unsigned int* __restrict__ outdeg, unsigned int* __restrict__ indeg,
                              int N, int nreg, int regsz) {
    int bin = blockIdx.x * blockDim.x + threadIdx.x;
    if (bin >= N) return;
    int r = bin / regsz;
    int lbin = bin - r * regsz;
    unsigned int so = 0, si = 0;
    for (int s = 0; s < NSLICE; ++s) {
        unsigned int v = partial[(size_t)(s * nreg + r) * regsz + lbin];
        so += v & 0xffffu;
        si += v >> 16;
    }
    outdeg[bin] = so;
    indeg[bin] = si;
}

__global__ void transform_kernel(const float* __restrict__ feat, const float* __restrict__ weight,
                                 const float* __restrict__ wtype, const int* __restrict__ tinfo,
                                 const unsigned int* __restrict__ outdeg,
                                 float* __restrict__ h, int N) {
    __shared__ float W[64 * 64];
    int t = threadIdx.x;
    const float4* w4 = (const float4*)weight;
    float4* W4 = (float4*)W;
#pragma unroll
    for (int i = 0; i < 4; ++i) W4[t + i * 256] = w4[t + i * 256];
    __syncthreads();

    int row = blockIdx.x * blockDim.x + t;
    if (row >= N) return;

    float s = rsqrtf(fmaxf((float)outdeg[row], 1.0f)) * wtype[tinfo[row]];

    float acc[64];
#pragma unroll
    for (int j = 0; j < 64; ++j) acc[j] = 0.0f;

    const float4* frow = (const float4*)(feat + (size_t)row * 64);
    for (int k4 = 0; k4 < 16; ++k4) {
        float4 a4 = frow[k4];
#pragma unroll
        for (int kk = 0; kk < 4; ++kk) {
            float a = (kk == 0) ? a4.x : (kk == 1) ? a4.y : (kk == 2) ? a4.z : a4.w;
            const float4* wr = (const float4*)&W[(k4 * 4 + kk) * 64];
#pragma unroll
            for (int j4 = 0; j4 < 16; ++j4) {
                float4 w = wr[j4];  // wave-uniform LDS address -> broadcast
                acc[j4 * 4 + 0] += a * w.x;
                acc[j4 * 4 + 1] += a * w.y;
                acc[j4 * 4 + 2] += a * w.z;
                acc[j4 * 4 + 3] += a * w.w;
            }
        }
    }

    float4* hrow = (float4*)(h + (size_t)row * 64);
#pragma unroll
    for (int j4 = 0; j4 < 16; ++j4) {
        float4 v;
        v.x = acc[j4 * 4 + 0] * s;
        v.y = acc[j4 * 4 + 1] * s;
        v.z = acc[j4 * 4 + 2] * s;
        v.w = acc[j4 * 4 + 3] * s;
        hrow[j4] = v;
    }
}

__global__ void scan1_kernel(const unsigned int* __restrict__ indeg,
                             unsigned int* __restrict__ offsets,
                             unsigned int* __restrict__ blockSums, int N) {
    __shared__ unsigned int sdata[256];
    int t = threadIdx.x;
    int base = blockIdx.x * SCAN_CHUNK;
    unsigned int v[4];
    unsigned int s = 0;
#pragma unroll
    for (int i = 0; i < 4; ++i) {
        int idx = base + t * 4 + i;
        v[i] = (idx < N) ? indeg[idx] : 0u;
        s += v[i];
    }
    sdata[t] = s;
    __syncthreads();
    for (int off = 1; off < 256; off <<= 1) {
        unsigned int x = (t >= off) ? sdata[t - off] : 0u;
        __syncthreads();
        sdata[t] += x;
        __syncthreads();
    }
    if (t == 255) blockSums[blockIdx.x] = sdata[255];
    unsigned int run = sdata[t] - s;
#pragma unroll
    for (int i = 0; i < 4; ++i) {
        int idx = base + t * 4 + i;
        if (idx < N) offsets[idx] = run;
        run += v[i];
    }
}

__global__ void scan2_kernel(unsigned int* __restrict__ blockSums, int nb) {
    __shared__ unsigned int sdata[1024];
    int t = threadIdx.x;
    unsigned int v = (t < nb) ? blockSums[t] : 0u;
    sdata[t] = v;
    __syncthreads();
    for (int off = 1; off < 1024; off <<= 1) {
        unsigned int x = (t >= off) ? sdata[t - off] : 0u;
        __syncthreads();
        sdata[t] += x;
        __syncthreads();
    }
    if (t < nb) blockSums[t] = sdata[t] - v;
}

__global__ void scan3_kernel(unsigned int* __restrict__ offsets,
                             const unsigned int* __restrict__ blockSums,
                             unsigned int* __restrict__ cursor, int N) {
    int i = blockIdx.x * blockDim.x + threadIdx.x;
    if (i < N) {
        unsigned int o = offsets[i] + blockSums[i / SCAN_CHUNK];
        offsets[i] = o;
        cursor[i] = o;
    }
}

__global__ void bucket_team_kernel(const int* __restrict__ src, const int* __restrict__ dst,
                                   unsigned int* __restrict__ cursor,
                                   int* __restrict__ sorted_src, int E, int regsz) {
    int team = blockIdx.x & (NTEAM - 1);
    int blk  = blockIdx.x >> 3;
    int lo = team * regsz, hi = lo + regsz;
    int tid = blk * blockDim.x + threadIdx.x;
    int stride = (gridDim.x >> 3) * blockDim.x;
    for (int e = tid; e < E; e += stride) {
        int d = dst[e];
        if (d >= lo && d < hi) {
            unsigned int pos = atomicAdd(&cursor[d], 1u);
            sorted_src[pos] = src[e];   // team's contiguous slice -> XCD-local, combines in L2
        }
    }
}

__global__ void gather_kernel(const int* __restrict__ sorted_src,
                              const unsigned int* __restrict__ offsets,
                              const unsigned int* __restrict__ indeg,
                              const float* __restrict__ h, const float* __restrict__ bias,
                              float* __restrict__ out, int N) {
    int lane = threadIdx.x & 63;
    int node = blockIdx.x * (blockDim.x >> 6) + (threadIdx.x >> 6);
    if (node >= N) return;
    unsigned int beg = offsets[node];
    unsigned int cnt = indeg[node];
    unsigned int i = beg, end = beg + cnt;
    float acc = 0.0f;
    for (; i + 4 <= end; i += 4) {
        int s0 = sorted_src[i + 0];
        int s1 = sorted_src[i + 1];
        int s2 = sorted_src[i + 2];
        int s3 = sorted_src[i + 3];
        float v0 = h[(size_t)s0 * 64 + lane];
        float v1 = h[(size_t)s1 * 64 + lane];
        float v2 = h[(size_t)s2 * 64 + lane];
        float v3 = h[(size_t)s3 * 64 + lane];
        acc += (v0 + v1) + (v2 + v3);
    }
    for (; i < end; ++i) acc += h[(size_t)sorted_src[i] * 64 + lane];
    float sc = rsqrtf(fmaxf((float)cnt, 1.0f));
    out[(size_t)node * 64 + lane] = acc * sc + bias[lane];
}

extern "C" void kernel_launch(void* const* d_in, const int* in_sizes, int n_in,
                              void* d_out, int out_size, void* d_ws, size_t ws_size,
                              hipStream_t stream) {
    const float* feat   = (const float*)d_in[0];
    const float* weight = (const float*)d_in[1];
    const float* wtype  = (const float*)d_in[2];
    const float* bias   = (const float*)d_in[3];
    const int*   src    = (const int*)d_in[4];
    const int*   dst    = (const int*)d_in[5];
    const int*   tinfo  = (const int*)d_in[6];

    int E = in_sizes[4];
    int N = in_sizes[6];
    float* out = (float*)d_out;

    int nreg  = (N + MAXREG - 1) / MAXREG;          // 8 for N=100k
    int regsz = (N + nreg - 1) / nreg;              // 12500
    int chunk = (((E + NSLICE - 1) / NSLICE) + 3) & ~3;  // 25000, mult of 4
    int team_regsz = (N + NTEAM - 1) / NTEAM;

    // Workspace: [A: h ALIASES partials (partials dead before transform)] | outdeg |
    //            indeg | offsets | cursor | blockSums | sorted_src
    size_t h_bytes = (size_t)N * 64 * sizeof(float);
    size_t partial_bytes = (size_t)NSLICE * nreg * regsz * sizeof(unsigned int);
    size_t blobA = h_bytes > partial_bytes ? h_bytes : partial_bytes;

    char* ws = (char*)d_ws;
    float* h = (float*)ws;
    unsigned int* partial = (unsigned int*)ws;          ws += blobA;
    unsigned int* outdeg    = (unsigned int*)ws;        ws += (size_t)N * sizeof(unsigned int);
    unsigned int* indeg     = (unsigned int*)ws;        ws += (size_t)N * sizeof(unsigned int);
    unsigned int* offsets   = (unsigned int*)ws;        ws += (size_t)N * sizeof(unsigned int);
    unsigned int* cursor    = (unsigned int*)ws;        ws += (size_t)N * sizeof(unsigned int);
    unsigned int* blockSums = (unsigned int*)ws;        ws += 1024 * sizeof(unsigned int);
    int* sorted_src = (int*)ws;

    hist_kernel<<<NSLICE * nreg, THREADS, 0, stream>>>(src, dst, partial, E, nreg, regsz, chunk, N);
    reduce_kernel<<<(N + THREADS - 1) / THREADS, THREADS, 0, stream>>>(partial, outdeg, indeg, N, nreg, regsz);

    transform_kernel<<<(N + THREADS - 1) / THREADS, THREADS, 0, stream>>>(
        feat, weight, wtype, tinfo, outdeg, h, N);

    int nb = (N + SCAN_CHUNK - 1) / SCAN_CHUNK;
    scan1_kernel<<<nb, 256, 0, stream>>>(indeg, offsets, blockSums, N);
    scan2_kernel<<<1, 1024, 0, stream>>>(blockSums, nb);
    scan3_kernel<<<(N + THREADS - 1) / THREADS, THREADS, 0, stream>>>(offsets, blockSums, cursor, N);

    int team_grid = NTEAM * BLOCKS_PER_TEAM;
    bucket_team_kernel<<<team_grid, THREADS, 0, stream>>>(src, dst, cursor, sorted_src, E, team_regsz);

    int waves_per_block = THREADS / 64;
    int gather_blocks = (N + waves_per_block - 1) / waves_per_block;
    gather_kernel<<<gather_blocks, THREADS, 0, stream>>>(sorted_src, offsets, indeg, h, bias, out, N);
}

// Round 6
// 195.231 us; speedup vs baseline: 2.7335x; 1.0721x over previous
//
#include <hip/hip_runtime.h>

// REConv forward via dst-CSR gather. All scattered GLOBAL atomics eliminated
// (R4: scattered global atomics are memory-side RMWs, write-through, ~26G/s).
//   1. hist:      per-(slice,region) LDS histograms, packed u32 (lo16=out, hi16=in)
//   2. reduce:    sum slice partials -> outdeg, indeg
//   3. scan1/2/3: exclusive prefix sum of indeg -> offsets
//   4. pboff:     partial[s][bin] := global start offset of slice s's segment of bin
//   5. bucket_lds: block (slice,region): LDS cursors seeded from pboff; LDS atomics
//                  assign positions; disjoint sorted_src ranges; region r -> XCD r
//   6. transform: h16 = bf16((feat * outdeg^-1/2 * wtype[type]) @ W)  (aliases partial)
//   7. gather:    one wave per dst node; bf16 h gather (halved bytes + better L2 fit),
//                 fused indeg^-1/2 + bias
// F_IN = F_OUT = 64 hardcoded.

#define THREADS 256
#define SCAN_CHUNK 1024
#define NSLICE 64
#define MAXREG 12800   // bins per region cap; LDS = 51.2 KB

__device__ __forceinline__ unsigned f2bf(float f) {   // RTNE f32->bf16 bits
    unsigned x = __float_as_uint(f);
    return (x + 0x7fffu + ((x >> 16) & 1u)) >> 16;
}
__device__ __forceinline__ float bf2f(unsigned short u) {
    return __uint_as_float((unsigned)u << 16);
}

__global__ void hist_kernel(const int* __restrict__ src, const int* __restrict__ dst,
                            unsigned int* __restrict__ partial,
                            int E, int nreg, int regsz, int chunk, int N) {
    __shared__ unsigned int hist[MAXREG];
    int r = blockIdx.x % nreg;
    int s = blockIdx.x / nreg;
    int lo = r * regsz;
    int hi = min(lo + regsz, N);
    int nb = hi - lo;
    int t = threadIdx.x;
    for (int b = t; b < nb; b += THREADS) hist[b] = 0u;
    __syncthreads();

    int ebeg = s * chunk;
    int eend = min(E, ebeg + chunk);
    int main_end = ebeg + ((eend - ebeg) & ~3);
    for (int i = ebeg + t * 4; i + 4 <= main_end; i += THREADS * 4) {
        int4 s4 = *(const int4*)(src + i);
        int4 d4 = *(const int4*)(dst + i);
        if (s4.x >= lo && s4.x < hi) atomicAdd(&hist[s4.x - lo], 1u);
        if (s4.y >= lo && s4.y < hi) atomicAdd(&hist[s4.y - lo], 1u);
        if (s4.z >= lo && s4.z < hi) atomicAdd(&hist[s4.z - lo], 1u);
        if (s4.w >= lo && s4.w < hi) atomicAdd(&hist[s4.w - lo], 1u);
        if (d4.x >= lo && d4.x < hi) atomicAdd(&hist[d4.x - lo], 65536u);
        if (d4.y >= lo && d4.y < hi) atomicAdd(&hist[d4.y - lo], 65536u);
        if (d4.z >= lo && d4.z < hi) atomicAdd(&hist[d4.z - lo], 65536u);
        if (d4.w >= lo && d4.w < hi) atomicAdd(&hist[d4.w - lo], 65536u);
    }
    for (int i = main_end + t; i < eend; i += THREADS) {
        int sv = src[i], dv = dst[i];
        if (sv >= lo && sv < hi) atomicAdd(&hist[sv - lo], 1u);
        if (dv >= lo && dv < hi) atomicAdd(&hist[dv - lo], 65536u);
    }
    __syncthreads();
    unsigned int* pp = partial + (size_t)blockIdx.x * regsz;
    for (int b = t; b < nb; b += THREADS) pp[b] = hist[b];
}

__global__ void reduce_kernel(const unsigned int* __restrict__ partial,
                              unsigned int* __restrict__ outdeg, unsigned int* __restrict__ indeg,
                              int N, int nreg, int regsz) {
    int bin = blockIdx.x * blockDim.x + threadIdx.x;
    if (bin >= N) return;
    int r = bin / regsz;
    int lbin = bin - r * regsz;
    unsigned int so = 0, si = 0;
    for (int s = 0; s < NSLICE; ++s) {
        unsigned int v = partial[(size_t)(s * nreg + r) * regsz + lbin];
        so += v & 0xffffu;
        si += v >> 16;
    }
    outdeg[bin] = so;
    indeg[bin] = si;
}

__global__ void scan1_kernel(const unsigned int* __restrict__ indeg,
                             unsigned int* __restrict__ offsets,
                             unsigned int* __restrict__ blockSums, int N) {
    __shared__ unsigned int sdata[256];
    int t = threadIdx.x;
    int base = blockIdx.x * SCAN_CHUNK;
    unsigned int v[4];
    unsigned int s = 0;
#pragma unroll
    for (int i = 0; i < 4; ++i) {
        int idx = base + t * 4 + i;
        v[i] = (idx < N) ? indeg[idx] : 0u;
        s += v[i];
    }
    sdata[t] = s;
    __syncthreads();
    for (int off = 1; off < 256; off <<= 1) {
        unsigned int x = (t >= off) ? sdata[t - off] : 0u;
        __syncthreads();
        sdata[t] += x;
        __syncthreads();
    }
    if (t == 255) blockSums[blockIdx.x] = sdata[255];
    unsigned int run = sdata[t] - s;
#pragma unroll
    for (int i = 0; i < 4; ++i) {
        int idx = base + t * 4 + i;
        if (idx < N) offsets[idx] = run;
        run += v[i];
    }
}

__global__ void scan2_kernel(unsigned int* __restrict__ blockSums, int nb) {
    __shared__ unsigned int sdata[1024];
    int t = threadIdx.x;
    unsigned int v = (t < nb) ? blockSums[t] : 0u;
    sdata[t] = v;
    __syncthreads();
    for (int off = 1; off < 1024; off <<= 1) {
        unsigned int x = (t >= off) ? sdata[t - off] : 0u;
        __syncthreads();
        sdata[t] += x;
        __syncthreads();
    }
    if (t < nb) blockSums[t] = sdata[t] - v;
}

__global__ void scan3_kernel(unsigned int* __restrict__ offsets,
                             const unsigned int* __restrict__ blockSums, int N) {
    int i = blockIdx.x * blockDim.x + threadIdx.x;
    if (i < N) offsets[i] += blockSums[i / SCAN_CHUNK];
}

// partial[s][r][lbin] := global start offset of slice s's segment of bin (r,lbin).
__global__ void pboff_kernel(unsigned int* __restrict__ partial,
                             const unsigned int* __restrict__ offsets,
                             int N, int nreg, int regsz) {
    int bin = blockIdx.x * blockDim.x + threadIdx.x;
    if (bin >= N) return;
    int r = bin / regsz;
    int lbin = bin - r * regsz;
    unsigned int base = offsets[bin];
    for (int s = 0; s < NSLICE; ++s) {
        size_t idx = (size_t)(s * nreg + r) * regsz + lbin;
        unsigned int cnt = partial[idx] >> 16;   // indeg count of this (slice,bin)
        partial[idx] = base;
        base += cnt;
    }
}

// Zero global atomics: LDS cursors seeded with per-slice offsets; disjoint output ranges.
__global__ void bucket_lds_kernel(const int* __restrict__ src, const int* __restrict__ dst,
                                  const unsigned int* __restrict__ partial,
                                  int* __restrict__ sorted_src,
                                  int E, int nreg, int regsz, int chunk, int N) {
    __shared__ unsigned int cur[MAXREG];
    int r = blockIdx.x % nreg;   // region r -> XCD r (blockIdx%8 round-robin): writes stay XCD-local
    int s = blockIdx.x / nreg;
    int lo = r * regsz;
    int hi = min(lo + regsz, N);
    int nb = hi - lo;
    int t = threadIdx.x;
    const unsigned int* pb = partial + (size_t)blockIdx.x * regsz;  // == (s*nreg+r)*regsz
    for (int b = t; b < nb; b += THREADS) cur[b] = pb[b];
    __syncthreads();

    int ebeg = s * chunk;
    int eend = min(E, ebeg + chunk);
    int main_end = ebeg + ((eend - ebeg) & ~3);
    for (int i = ebeg + t * 4; i + 4 <= main_end; i += THREADS * 4) {
        int4 d4 = *(const int4*)(dst + i);
        int4 s4 = *(const int4*)(src + i);
        if (d4.x >= lo && d4.x < hi) sorted_src[atomicAdd(&cur[d4.x - lo], 1u)] = s4.x;
        if (d4.y >= lo && d4.y < hi) sorted_src[atomicAdd(&cur[d4.y - lo], 1u)] = s4.y;
        if (d4.z >= lo && d4.z < hi) sorted_src[atomicAdd(&cur[d4.z - lo], 1u)] = s4.z;
        if (d4.w >= lo && d4.w < hi) sorted_src[atomicAdd(&cur[d4.w - lo], 1u)] = s4.w;
    }
    for (int i = main_end + t; i < eend; i += THREADS) {
        int d = dst[i];
        if (d >= lo && d < hi) sorted_src[atomicAdd(&cur[d - lo], 1u)] = src[i];
    }
}

__global__ void transform_kernel(const float* __restrict__ feat, const float* __restrict__ weight,
                                 const float* __restrict__ wtype, const int* __restrict__ tinfo,
                                 const unsigned int* __restrict__ outdeg,
                                 unsigned short* __restrict__ h16, int N) {
    __shared__ float W[64 * 64];
    int t = threadIdx.x;
    const float4* w4 = (const float4*)weight;
    float4* W4 = (float4*)W;
#pragma unroll
    for (int i = 0; i < 4; ++i) W4[t + i * 256] = w4[t + i * 256];
    __syncthreads();

    int row = blockIdx.x * blockDim.x + t;
    if (row >= N) return;

    float s = rsqrtf(fmaxf((float)outdeg[row], 1.0f)) * wtype[tinfo[row]];

    float acc[64];
#pragma unroll
    for (int j = 0; j < 64; ++j) acc[j] = 0.0f;

    const float4* frow = (const float4*)(feat + (size_t)row * 64);
    for (int k4 = 0; k4 < 16; ++k4) {
        float4 a4 = frow[k4];
#pragma unroll
        for (int kk = 0; kk < 4; ++kk) {
            float a = (kk == 0) ? a4.x : (kk == 1) ? a4.y : (kk == 2) ? a4.z : a4.w;
            const float4* wr = (const float4*)&W[(k4 * 4 + kk) * 64];
#pragma unroll
            for (int j4 = 0; j4 < 16; ++j4) {
                float4 w = wr[j4];  // wave-uniform LDS address -> broadcast
                acc[j4 * 4 + 0] += a * w.x;
                acc[j4 * 4 + 1] += a * w.y;
                acc[j4 * 4 + 2] += a * w.z;
                acc[j4 * 4 + 3] += a * w.w;
            }
        }
    }

    unsigned int* hrow = (unsigned int*)(h16 + (size_t)row * 64);
#pragma unroll
    for (int j2 = 0; j2 < 32; ++j2) {
        unsigned int p = f2bf(acc[2 * j2] * s) | (f2bf(acc[2 * j2 + 1] * s) << 16);
        hrow[j2] = p;
    }
}

__global__ void gather_kernel(const int* __restrict__ sorted_src,
                              const unsigned int* __restrict__ offsets,
                              const unsigned int* __restrict__ indeg,
                              const unsigned short* __restrict__ h16,
                              const float* __restrict__ bias,
                              float* __restrict__ out, int N) {
    int lane = threadIdx.x & 63;
    int node = blockIdx.x * (blockDim.x >> 6) + (threadIdx.x >> 6);
    if (node >= N) return;
    unsigned int beg = offsets[node];
    unsigned int cnt = indeg[node];
    unsigned int i = beg, end = beg + cnt;
    float acc = 0.0f;
    for (; i + 4 <= end; i += 4) {
        int s0 = sorted_src[i + 0];
        int s1 = sorted_src[i + 1];
        int s2 = sorted_src[i + 2];
        int s3 = sorted_src[i + 3];
        float v0 = bf2f(h16[(size_t)s0 * 64 + lane]);
        float v1 = bf2f(h16[(size_t)s1 * 64 + lane]);
        float v2 = bf2f(h16[(size_t)s2 * 64 + lane]);
        float v3 = bf2f(h16[(size_t)s3 * 64 + lane]);
        acc += (v0 + v1) + (v2 + v3);
    }
    for (; i < end; ++i) acc += bf2f(h16[(size_t)sorted_src[i] * 64 + lane]);
    float sc = rsqrtf(fmaxf((float)cnt, 1.0f));
    out[(size_t)node * 64 + lane] = acc * sc + bias[lane];
}

extern "C" void kernel_launch(void* const* d_in, const int* in_sizes, int n_in,
                              void* d_out, int out_size, void* d_ws, size_t ws_size,
                              hipStream_t stream) {
    const float* feat   = (const float*)d_in[0];
    const float* weight = (const float*)d_in[1];
    const float* wtype  = (const float*)d_in[2];
    const float* bias   = (const float*)d_in[3];
    const int*   src    = (const int*)d_in[4];
    const int*   dst    = (const int*)d_in[5];
    const int*   tinfo  = (const int*)d_in[6];

    int E = in_sizes[4];
    int N = in_sizes[6];
    float* out = (float*)d_out;

    int nreg  = (N + MAXREG - 1) / MAXREG;               // 8 for N=100k
    int regsz = (N + nreg - 1) / nreg;                   // 12500
    int chunk = (((E + NSLICE - 1) / NSLICE) + 3) & ~3;  // 25000, mult of 4

    // Workspace: [A: partial (25.6MB); h16 (12.8MB) aliases it AFTER bucket] |
    //            outdeg | indeg | offsets | blockSums | sorted_src
    size_t h_bytes = (size_t)N * 64 * sizeof(unsigned short);
    size_t partial_bytes = (size_t)NSLICE * nreg * regsz * sizeof(unsigned int);
    size_t blobA = h_bytes > partial_bytes ? h_bytes : partial_bytes;

    char* ws = (char*)d_ws;
    unsigned short* h16 = (unsigned short*)ws;
    unsigned int* partial = (unsigned int*)ws;          ws += blobA;
    unsigned int* outdeg    = (unsigned int*)ws;        ws += (size_t)N * sizeof(unsigned int);
    unsigned int* indeg     = (unsigned int*)ws;        ws += (size_t)N * sizeof(unsigned int);
    unsigned int* offsets   = (unsigned int*)ws;        ws += (size_t)N * sizeof(unsigned int);
    unsigned int* blockSums = (unsigned int*)ws;        ws += 1024 * sizeof(unsigned int);
    int* sorted_src = (int*)ws;

    hist_kernel<<<NSLICE * nreg, THREADS, 0, stream>>>(src, dst, partial, E, nreg, regsz, chunk, N);
    reduce_kernel<<<(N + THREADS - 1) / THREADS, THREADS, 0, stream>>>(partial, outdeg, indeg, N, nreg, regsz);

    int nb = (N + SCAN_CHUNK - 1) / SCAN_CHUNK;
    scan1_kernel<<<nb, 256, 0, stream>>>(indeg, offsets, blockSums, N);
    scan2_kernel<<<1, 1024, 0, stream>>>(blockSums, nb);
    scan3_kernel<<<(N + THREADS - 1) / THREADS, THREADS, 0, stream>>>(offsets, blockSums, N);

    pboff_kernel<<<(N + THREADS - 1) / THREADS, THREADS, 0, stream>>>(partial, offsets, N, nreg, regsz);
    bucket_lds_kernel<<<NSLICE * nreg, THREADS, 0, stream>>>(src, dst, partial, sorted_src, E, nreg, regsz, chunk, N);

    transform_kernel<<<(N + THREADS - 1) / THREADS, THREADS, 0, stream>>>(
        feat, weight, wtype, tinfo, outdeg, h16, N);

    int waves_per_block = THREADS / 64;
    int gather_blocks = (N + waves_per_block - 1) / waves_per_block;
    gather_kernel<<<gather_blocks, THREADS, 0, stream>>>(sorted_src, offsets, indeg, h16, bias, out, N);
}